// Round 4
// baseline (2936.907 us; speedup 1.0000x reference)
//
#include <hip/hip_runtime.h>
#include <hip/hip_bf16.h>

#define B_ 128
#define T_ 512
#define DIM_ 256
#define E_ 512
#define H_ 512
#define NB_ 32        // blocks per batch-group (sync domain)
#define NG_ 8         // batch groups
#define WROW 1032     // padded LDS row stride (1024 + 8) in bf16 elems
#define SLOT32 (B_ * H_ / 2)   // u32 per h-generation slot (32768)
#define SLOT64 (B_ * H_ / 4)   // u64 per slot
#define NSLOT (T_ + 1)         // h(0) .. h(512), no reuse -> no clear races

typedef __attribute__((ext_vector_type(8))) short short8;
typedef __attribute__((ext_vector_type(4))) float floatx4;
typedef unsigned long long ull_t;

__device__ __forceinline__ float sigmoidf_(float x) {
  return __fdividef(1.0f, 1.0f + __expf(-x));
}

// fast tanh via __expf; clamp avoids inf/inf NaN. Absmax-neutral vs tanhf
// (verified rounds 2-3). Also guarantees FINITE outputs -> f2bs never
// produces the 0xFFFF sentinel.
__device__ __forceinline__ float tanhf_(float x) {
  x = fminf(15.0f, fmaxf(-15.0f, x));
  const float e = __expf(2.0f * x);
  return __fdividef(e - 1.0f, e + 1.0f);
}

__device__ __forceinline__ short f2bs(float f) {
  __hip_bfloat16 h = __float2bfloat16(f);
  return *reinterpret_cast<short*>(&h);
}

// ---------------------------------------------------------------------------
// Kernel 0: convert We (fp32) -> bf16 workspace copy.
// ---------------------------------------------------------------------------
__global__ __launch_bounds__(256) void cvt_we(const float* __restrict__ src,
                                              __hip_bfloat16* __restrict__ dst,
                                              int n) {
  int i = blockIdx.x * 256 + threadIdx.x;
  if (i < n) dst[i] = __float2bfloat16(src[i]);
}

// ---------------------------------------------------------------------------
// Kernel 1: xe[b*T+t][e] = sum_d x_t[b,t,d] * We[e,d] + be[e]   (bf16 out)
// ---------------------------------------------------------------------------
__global__ __launch_bounds__(256) void embed_gemm(
    const float* __restrict__ A,             // x_t  [65536][256] fp32
    const __hip_bfloat16* __restrict__ W,    // Web  [512][256] bf16
    const float* __restrict__ bias,          // be   [512] fp32
    __hip_bfloat16* __restrict__ C)          // xe   [65536][512] bf16
{
  const int tid = threadIdx.x;
  const int lane = tid & 63;
  const int w = tid >> 6;
  const int q = lane >> 4;
  const int l15 = lane & 15;
  const int m0 = blockIdx.x * 32 + (w >> 1) * 16;
  const int n0 = (w & 1) * 256;

  const float* a_base = A + (size_t)(m0 + l15) * DIM_ + q * 8;

  floatx4 acc[16];
#pragma unroll
  for (int j = 0; j < 16; ++j) acc[j] = (floatx4){0.f, 0.f, 0.f, 0.f};

  for (int ks = 0; ks < 8; ++ks) {
    const float* ap = a_base + ks * 32;
    short8 a;
#pragma unroll
    for (int j = 0; j < 8; ++j) a[j] = f2bs(ap[j]);
    short8 bf[16];
#pragma unroll
    for (int j = 0; j < 16; ++j) {
      const short* b_ptr =
          (const short*)W + (n0 + j * 16 + l15) * DIM_ + ks * 32 + q * 8;
      bf[j] = *(const short8*)b_ptr;
    }
#pragma unroll
    for (int j = 0; j < 16; ++j)
      acc[j] = __builtin_amdgcn_mfma_f32_16x16x32_bf16(a, bf[j], acc[j], 0, 0, 0);
  }

#pragma unroll
  for (int j = 0; j < 16; ++j) {
    const int col = n0 + j * 16 + l15;
    const float bv = bias[col];
#pragma unroll
    for (int r = 0; r < 4; ++r) {
      const int row = m0 + q * 4 + r;
      C[(size_t)row * E_ + col] = __float2bfloat16(acc[j][r] + bv);
    }
  }
}

// ---------------------------------------------------------------------------
// Kernel 2: persistent LSTM. 256 blocks (1/CU), 256 thr.
// block = (group g = blk&7, slice jb = blk>>3): batches [g*16,g*16+16),
// dims [jb*16, jb*16+16), all 4 gates. Weights [64 rows x 1024 K] in LDS.
// Wave w: K-range [w*256,(w+1)*256): waves 0,1 -> xe (W), 2,3 -> h (R).
//
// SYNC v5 — sentinel-validated data polling (no flags, no publish):
//   hbuf has ONE slot per h-generation (513 slots, 67 MB), pre-filled with
//   0xFF bytes: u32 0xFFFFFFFF = 2x bf16 NaN, unreachable from f2bs(finite).
//   Producers just store their h-slice (relaxed agent u32). Consumers
//   (waves 2,3) speculatively load their chunks and validate each u32
//   against the sentinel; a chunk is consumed -- and its 4 MFMAs issued --
//   the moment it lands (wave-uniform via __all + miss-mask, so MFMA exec
//   is always full). This removes the producer pre-publish drain, the flag
//   store, the observe RTT, and the wake barrier from the serial chain:
//   handoff = one one-way store->load latency, consumption is progressive
//   (smooths max-of-32 skew). No slot reuse -> no clearing, no ABA.
//   2 __syncthreads/step, both pure pbuf WAR protection.
// ---------------------------------------------------------------------------
__global__ __launch_bounds__(256, 1) void lstm_persist(
    const float* __restrict__ h0,
    const float* __restrict__ c0,
    const float* __restrict__ Wi_, const float* __restrict__ bi_,
    const float* __restrict__ Wf_, const float* __restrict__ bf_,
    const float* __restrict__ Wg_, const float* __restrict__ bg_,
    const float* __restrict__ Wo_, const float* __restrict__ bo_,
    const float* __restrict__ Ri_, const float* __restrict__ Rf_,
    const float* __restrict__ Rg_, const float* __restrict__ Ro_,
    const __hip_bfloat16* __restrict__ xe,   // [B*T][E] bf16
    unsigned* __restrict__ hbuf32,           // [NSLOT][B][H/2] packed 2xbf16
    float* __restrict__ out)                 // hidden_seq | h_last | c_last
{
  extern __shared__ short wts[];             // 64 * WROW bf16 = 132096 B
  __shared__ float pbuf[4][4][16][16];       // [wave][gate][m][n] partials
  __shared__ float cbuf[16][16];             // fp32 cell state slice
  __shared__ float bias_s[4][16];

  const int tid = threadIdx.x;
  const int lane = tid & 63;
  const int w = tid >> 6;
  const int q = lane >> 4;
  const int l15 = lane & 15;
  const int blk = blockIdx.x;
  const int g = blk & 7;        // batch group (XCD-local under %8 round-robin)
  const int jb = blk >> 3;      // dim slice
  const int b0 = g * 16;
  const int d0 = jb * 16;
  ull_t* hbuf64 = (ull_t*)hbuf32;

  const float* Wp[4] = {Wi_, Wf_, Wg_, Wo_};
  const float* Rp[4] = {Ri_, Rf_, Rg_, Ro_};
  const float* bp[4] = {bi_, bf_, bg_, bo_};

  // ---- load weights into LDS: row (G*16+dl) = [W_G[d0+dl][0:512] | R_G[...]]
  for (int idx = tid; idx < 64 * 128; idx += 256) {
    const int row = idx >> 7;
    const int ch = idx & 127;
    const int G = row >> 4, dl = row & 15;
    const int k = ch * 8;
    const float* src = (k < 512) ? Wp[G] + (d0 + dl) * E_ + k
                                 : Rp[G] + (d0 + dl) * H_ + (k - 512);
    short8 v;
#pragma unroll
    for (int s = 0; s < 8; ++s) v[s] = f2bs(src[s]);
    *(short8*)&wts[row * WROW + k] = v;
  }
  if (tid < 64) {
    const int G = tid >> 4, n = tid & 15;
    bias_s[G][n] = bp[G][d0 + n];
  }
  {
    const int m = tid >> 4, n = tid & 15;
    cbuf[m][n] = c0[(b0 + m) * H_ + d0 + n];
  }
  // h0 -> slot 0, GROUP-LOCAL cooperative staging (each group's 32 blocks
  // cover its own 16 batch rows; consumers gate on the sentinel, so no
  // ordering flag is needed at all).
  if (tid < 128) {
    const int u = g * 4096 + jb * 128 + tid;   // u32 index within slot 0
    unsigned pk = (unsigned)(unsigned short)f2bs(h0[2 * u]) |
                  ((unsigned)(unsigned short)f2bs(h0[2 * u + 1]) << 16);
    __hip_atomic_store(&hbuf32[u], pk, __ATOMIC_RELAXED,
                       __HIP_MEMORY_SCOPE_AGENT);
  }

  __syncthreads();  // wts/cbuf/bias visible (and h0 stores issued)

  // per-wave pointers
  const short* xbase = (const short*)xe +
      (size_t)(b0 + l15) * T_ * E_ + w * 256 + q * 8;        // valid for w<2
  const int lds_base = l15 * WROW + w * 256 + q * 8;

  short8 cur[8];
  if (w < 2) {
#pragma unroll
    for (int s = 0; s < 8; ++s) cur[s] = *(const short8*)(xbase + s * 32);
  }

  const int m = tid >> 4, n = tid & 15;

  for (int t = 0; t < T_; ++t) {
    floatx4 acc[4];
#pragma unroll
    for (int G = 0; G < 4; ++G) acc[G] = (floatx4){0.f, 0.f, 0.f, 0.f};

    if (w >= 2) {
      // ---- sentinel-validated poll of h(t), progressive per-chunk MFMA ----
      const ull_t* hb = hbuf64 + (size_t)t * SLOT64 +
                        (b0 + l15) * (H_ / 4) + (w - 2) * 64 + q * 2;
      unsigned miss = 0xFFu;   // uniform across the wave (updated under __all)
      ull_t ta[8], tb[8];
      while (miss) {
#pragma unroll
        for (int s = 0; s < 8; ++s)
          if (miss & (1u << s)) {
            ta[s] = __hip_atomic_load(hb + s * 8, __ATOMIC_RELAXED,
                                      __HIP_MEMORY_SCOPE_AGENT);
            tb[s] = __hip_atomic_load(hb + s * 8 + 1, __ATOMIC_RELAXED,
                                      __HIP_MEMORY_SCOPE_AGENT);
          }
#pragma unroll
        for (int s = 0; s < 8; ++s)
          if (miss & (1u << s)) {
            const unsigned a0 = (unsigned)ta[s];
            const unsigned a1 = (unsigned)(ta[s] >> 32);
            const unsigned c0_ = (unsigned)tb[s];
            const unsigned c1 = (unsigned)(tb[s] >> 32);
            const bool fresh =
                (a0 != 0xFFFFFFFFu) & (a1 != 0xFFFFFFFFu) &
                (c0_ != 0xFFFFFFFFu) & (c1 != 0xFFFFFFFFu);
            if (__all((int)fresh)) {       // uniform -> MFMA exec is full
              union { ull_t u[2]; short8 v8; } uu;
              uu.u[0] = ta[s];
              uu.u[1] = tb[s];
#pragma unroll
              for (int G = 0; G < 4; ++G) {
                short8 bfr =
                    *(const short8*)&wts[G * 16 * WROW + lds_base + s * 32];
                acc[G] = __builtin_amdgcn_mfma_f32_16x16x32_bf16(uu.v8, bfr,
                                                                 acc[G], 0, 0, 0);
              }
              miss &= ~(1u << s);
            }
          }
      }
    } else {
      // ---- x-partials from prefetched fragments ----
#pragma unroll
      for (int s = 0; s < 8; ++s)
#pragma unroll
        for (int G = 0; G < 4; ++G) {
          short8 bfr = *(const short8*)&wts[G * 16 * WROW + lds_base + s * 32];
          acc[G] = __builtin_amdgcn_mfma_f32_16x16x32_bf16(cur[s], bfr, acc[G],
                                                           0, 0, 0);
        }
      // prefetch next step's xe fragments (read-only: safe across barriers)
      if (t + 1 < T_) {
        const short* xp = xbase + (size_t)(t + 1) * E_;
#pragma unroll
        for (int s = 0; s < 8; ++s) cur[s] = *(const short8*)(xp + s * 32);
      }
    }

#pragma unroll
    for (int G = 0; G < 4; ++G)
#pragma unroll
      for (int r = 0; r < 4; ++r)
        pbuf[w][G][q * 4 + r][l15] = acc[G][r];
    __syncthreads();  // sync1: all 4 waves' partials ready

    // ---- combine + activations ----
    float pre[4];
#pragma unroll
    for (int G = 0; G < 4; ++G)
      pre[G] = pbuf[0][G][m][n] + pbuf[1][G][m][n] + pbuf[2][G][m][n] +
               pbuf[3][G][m][n] + bias_s[G][n];
    const float iv = sigmoidf_(pre[0]);
    const float fv = sigmoidf_(pre[1]);
    const float gv = tanhf_(pre[2]);
    const float ov = sigmoidf_(pre[3]);
    const float cv = gv * iv + fv * cbuf[m][n];
    cbuf[m][n] = cv;
    const float hval = ov * tanhf_(cv);

    // publish h(t+1): pack 2xbf16 with lane n^1, ONE relaxed agent u32 store.
    // No flag, no drain: the store itself is the publication.
    {
      unsigned hv = (unsigned)(unsigned short)f2bs(hval);
      unsigned ov2 = __shfl_xor(hv, 1);
      if ((n & 1) == 0) {
        unsigned pk = hv | (ov2 << 16);
        __hip_atomic_store(
            &hbuf32[(size_t)(t + 1) * SLOT32 + (b0 + m) * (H_ / 2) +
                    ((d0 + n) >> 1)],
            pk, __ATOMIC_RELAXED, __HIP_MEMORY_SCOPE_AGENT);
      }
    }

    // out stores (fp32, exact h): ack folds into sync2's drain, which gates
    // only this block's next sync1 arrival (covered by next step's h-poll).
    out[((size_t)(b0 + m) * T_ + t) * H_ + d0 + n] = hval;
    if (t == T_ - 1) {
      out[(size_t)B_ * T_ * H_ + (b0 + m) * H_ + d0 + n] = hval;
      out[(size_t)B_ * T_ * H_ + B_ * H_ + (b0 + m) * H_ + d0 + n] = cv;
    }

    __syncthreads();  // sync2: pbuf WAR (next step's writes vs this combine)
  }
}

// ---------------------------------------------------------------------------
extern "C" void kernel_launch(void* const* d_in, const int* in_sizes, int n_in,
                              void* d_out, int out_size, void* d_ws,
                              size_t ws_size, hipStream_t stream) {
  const float* x_t = (const float*)d_in[0];
  const float* h0  = (const float*)d_in[1];
  const float* c0  = (const float*)d_in[2];
  const float* We  = (const float*)d_in[3];
  const float* be  = (const float*)d_in[4];
  const float* Wf  = (const float*)d_in[5];
  const float* bf_ = (const float*)d_in[6];
  const float* Wi  = (const float*)d_in[7];
  const float* bi  = (const float*)d_in[8];
  const float* Wg  = (const float*)d_in[9];
  const float* bg  = (const float*)d_in[10];
  const float* Wo  = (const float*)d_in[11];
  const float* bo  = (const float*)d_in[12];
  const float* Rf  = (const float*)d_in[13];
  const float* Ri  = (const float*)d_in[14];
  const float* Rg  = (const float*)d_in[15];
  const float* Ro  = (const float*)d_in[16];
  float* out = (float*)d_out;

  // workspace layout
  const size_t HBUF_BYTES = (size_t)NSLOT * SLOT32 * 4;   // 67,239,936 B
  char* ws = (char*)d_ws;
  unsigned* hbuf = (unsigned*)ws;
  __hip_bfloat16* Web = (__hip_bfloat16*)(ws + 67240960);         // 262144 B
  __hip_bfloat16* xe  = (__hip_bfloat16*)(ws + 67240960 + 262144);

  // sentinel-fill ALL slots: u32 0xFFFFFFFF = 2x bf16 NaN, unreachable from
  // f2bs(finite). Re-poisoned every launch (graph replay safe).
  hipMemsetAsync(hbuf, 0xFF, HBUF_BYTES, stream);

  cvt_we<<<(E_ * DIM_ + 255) / 256, 256, 0, stream>>>(We, Web, E_ * DIM_);

  embed_gemm<<<(B_ * T_) / 32, 256, 0, stream>>>(x_t, Web, be, xe);

  const size_t lds_bytes = 64 * WROW * sizeof(short);  // 132096
  lstm_persist<<<NG_ * NB_, 256, lds_bytes, stream>>>(
      h0, c0, Wi, bi, Wf, bf_, Wg, bg, Wo, bo, Ri, Rf, Rg, Ro, xe, hbuf, out);
}